// Round 11
// baseline (217.516 us; speedup 1.0000x reference)
//
#include <hip/hip_runtime.h>

// out = x * diag (broadcast over last axis). x: 32768 x 4096 f32, diag: 4096 f32.
// R11: WAVE-contiguous chunking. Each of the 8192 waves owns a dense 64KB
// region and walks it sequentially (1KB per access, stride 1KB) — the wave's
// DRAM address stream is sequential regardless of inter-wave scheduler drift.
// (R10's block-chunk is only sequential if 16 waves stay in lockstep.)
// diag reloaded per iter (R4: hoist vs reload = neutral; hoisting here would
// need 16 dv regs and break the 64-VGPR full-occupancy budget).
// Keeps: nt load+store (R6/R7 wins), 512x1024 launch (R10 win).

#define CH4 1024   // 4096 channels / 4 floats per float4

typedef float f32x4 __attribute__((ext_vector_type(4)));

// Wave-chunk kernel: total_waves = grid*blockDim/64; wchunk = n4/total_waves.
// Requires wchunk % 64 == 0 (whole wave-accesses) and exact division.
__global__ __launch_bounds__(1024)
void DiagonalLinear_wavechunk(const f32x4* __restrict__ x,
                              const f32x4* __restrict__ diag,
                              f32x4* __restrict__ out,
                              unsigned int wchunk) {
    const unsigned int lane  = threadIdx.x & 63u;
    const unsigned int gwave = (blockIdx.x * blockDim.x + threadIdx.x) >> 6;
    unsigned int idx = gwave * wchunk + lane;
    const unsigned int end = gwave * wchunk + wchunk;
    for (; idx < end; idx += 64) {
        f32x4 v  = __builtin_nontemporal_load(&x[idx]);
        f32x4 dv = diag[idx & (CH4 - 1)];   // L1 hit
        __builtin_nontemporal_store(v * dv, &out[idx]);
    }
}

// Fallback 1: R10 wide block-chunk kernel (1024 threads).
__global__ __launch_bounds__(1024)
void DiagonalLinear_wide(const f32x4* __restrict__ x,
                         const f32x4* __restrict__ diag,
                         f32x4* __restrict__ out,
                         unsigned int chunk) {
    const unsigned int tid = threadIdx.x;
    const f32x4 dv = diag[tid];
    unsigned int idx = blockIdx.x * chunk + tid;
    const unsigned int end = blockIdx.x * chunk + chunk;
#pragma unroll 4
    for (; idx < end; idx += 1024) {
        f32x4 v = __builtin_nontemporal_load(&x[idx]);
        __builtin_nontemporal_store(v * dv, &out[idx]);
    }
}

// Fallback 2: grid-stride (general shapes).
template <bool HOIST>
__global__ __launch_bounds__(256)
void DiagonalLinear_gs(const f32x4* __restrict__ x,
                       const f32x4* __restrict__ diag,
                       f32x4* __restrict__ out,
                       unsigned int n4) {
    const unsigned int stride = gridDim.x * blockDim.x;
    unsigned int i = blockIdx.x * blockDim.x + threadIdx.x;
    f32x4 dv;
    if (HOIST) dv = diag[i & (CH4 - 1)];
    for (; i < n4; i += stride) {
        f32x4 xv = __builtin_nontemporal_load(&x[i]);
        f32x4 dvv = HOIST ? dv : diag[i & (CH4 - 1)];
        __builtin_nontemporal_store(xv * dvv, &out[i]);
    }
}

extern "C" void kernel_launch(void* const* d_in, const int* in_sizes, int n_in,
                              void* d_out, int out_size, void* d_ws, size_t ws_size,
                              hipStream_t stream) {
    const float* x    = (const float*)d_in[0];
    const float* diag = (const float*)d_in[1];
    float* out        = (float*)d_out;

    const long long n  = (long long)in_sizes[0];   // 32768*4096
    const unsigned int n4 = (unsigned int)(n / 4); // 2^25, fits u32

    // Wave-chunk path: 512 blocks x 1024 threads = 8192 waves.
    {
        const int grid = 512, block = 1024;
        const unsigned int nwaves = (unsigned int)grid * block / 64;  // 8192
        const unsigned int wchunk = n4 / nwaves;                      // 4096
        if ((long long)nwaves * wchunk == (long long)n4 && (wchunk & 63u) == 0) {
            DiagonalLinear_wavechunk<<<grid, block, 0, stream>>>(
                (const f32x4*)x, (const f32x4*)diag, (f32x4*)out, wchunk);
            return;
        }
    }
    // Wide block-chunk path.
    {
        const int grid = 512;
        const unsigned int chunk = n4 / grid;
        if ((long long)grid * chunk == (long long)n4 && (chunk & (CH4 - 1)) == 0) {
            DiagonalLinear_wide<<<grid, 1024, 0, stream>>>(
                (const f32x4*)x, (const f32x4*)diag, (f32x4*)out, chunk);
            return;
        }
    }
    // General path.
    const int block = 256;
    long long want = ((long long)n4 + block - 1) / block;
    int g = (int)(want < 2048 ? want : 2048);
    const unsigned int stride = (unsigned int)g * block;
    if ((stride & (CH4 - 1)) == 0) {
        DiagonalLinear_gs<true><<<g, block, 0, stream>>>(
            (const f32x4*)x, (const f32x4*)diag, (f32x4*)out, n4);
    } else {
        DiagonalLinear_gs<false><<<g, block, 0, stream>>>(
            (const f32x4*)x, (const f32x4*)diag, (f32x4*)out, n4);
    }
}

// Round 12
// 192.829 us; speedup vs baseline: 1.1280x; 1.1280x over previous
//
#include <hip/hip_runtime.h>

// out = x * diag (broadcast over last axis). x: 32768 x 4096 f32, diag: 4096 f32.
// R12 = REVERT to R10 (best: 192.5us, 5.58 TB/s, 89% of float4-copy ceiling).
// Final structure and why (ladder evidence):
//  - nt load + nt store: streaming data bypasses L2/L3 (R6 +4%, R7 +3%)
//  - block-contiguous chunks (R8 +3%) with 1024-thread blocks (R10 +3%):
//    each block-wide access = 16KB aligned contiguous burst; 512 streams.
//  - one diag reg per thread (tid spans exactly CH4=1024).
//  - REJECTED by A/B: manual load batching (R5 -14%, R9 neutral),
//    wave-contiguous chunks (R11 -13%), 64-bit indexing, non-nt paths.

#define CH4 1024   // 4096 channels / 4 floats per float4

typedef float f32x4 __attribute__((ext_vector_type(4)));

// Wide kernel: blockDim.x == 1024 == CH4; requires chunk % 1024 == 0.
__global__ __launch_bounds__(1024)
void DiagonalLinear_wide(const f32x4* __restrict__ x,
                         const f32x4* __restrict__ diag,
                         f32x4* __restrict__ out,
                         unsigned int chunk) {
    const unsigned int tid = threadIdx.x;       // 0..1023 == channel group
    const f32x4 dv = diag[tid];                 // one channel group per thread
    unsigned int idx = blockIdx.x * chunk + tid;
    const unsigned int end = blockIdx.x * chunk + chunk;
#pragma unroll 4
    for (; idx < end; idx += 1024) {
        f32x4 v = __builtin_nontemporal_load(&x[idx]);
        __builtin_nontemporal_store(v * dv, &out[idx]);
    }
}

// Fallback: R8 chunked kernel (256-thread blocks).
__global__ __launch_bounds__(256)
void DiagonalLinear_chunked(const f32x4* __restrict__ x,
                            const f32x4* __restrict__ diag,
                            f32x4* __restrict__ out,
                            unsigned int chunk) {
    const unsigned int tid  = threadIdx.x;
    const unsigned int iters = chunk >> 8;
    const f32x4 d0 = diag[tid];
    const f32x4 d1 = diag[tid + 256];
    const f32x4 d2 = diag[tid + 512];
    const f32x4 d3 = diag[tid + 768];
    unsigned int idx = blockIdx.x * chunk + tid;
    for (unsigned int k = 0; k < iters; k += 4, idx += 1024) {
        f32x4 a = __builtin_nontemporal_load(&x[idx]);
        __builtin_nontemporal_store(a * d0, &out[idx]);
        f32x4 b = __builtin_nontemporal_load(&x[idx + 256]);
        __builtin_nontemporal_store(b * d1, &out[idx + 256]);
        f32x4 c = __builtin_nontemporal_load(&x[idx + 512]);
        __builtin_nontemporal_store(c * d2, &out[idx + 512]);
        f32x4 d = __builtin_nontemporal_load(&x[idx + 768]);
        __builtin_nontemporal_store(d * d3, &out[idx + 768]);
    }
}

// General fallback: grid-stride.
template <bool HOIST>
__global__ __launch_bounds__(256)
void DiagonalLinear_gs(const f32x4* __restrict__ x,
                       const f32x4* __restrict__ diag,
                       f32x4* __restrict__ out,
                       unsigned int n4) {
    const unsigned int stride = gridDim.x * blockDim.x;
    unsigned int i = blockIdx.x * blockDim.x + threadIdx.x;
    f32x4 dv;
    if (HOIST) dv = diag[i & (CH4 - 1)];
    for (; i < n4; i += stride) {
        f32x4 xv = __builtin_nontemporal_load(&x[i]);
        f32x4 dvv = HOIST ? dv : diag[i & (CH4 - 1)];
        __builtin_nontemporal_store(xv * dvv, &out[i]);
    }
}

extern "C" void kernel_launch(void* const* d_in, const int* in_sizes, int n_in,
                              void* d_out, int out_size, void* d_ws, size_t ws_size,
                              hipStream_t stream) {
    const float* x    = (const float*)d_in[0];
    const float* diag = (const float*)d_in[1];
    float* out        = (float*)d_out;

    const long long n  = (long long)in_sizes[0];   // 32768*4096
    const unsigned int n4 = (unsigned int)(n / 4); // 2^25, fits u32

    // Wide path: 512 blocks x 1024 threads, chunk multiple of 1024.
    {
        const int grid = 512;
        const unsigned int chunk = n4 / grid;      // 65536 float4 per block
        if ((long long)grid * chunk == (long long)n4 && (chunk & (CH4 - 1)) == 0) {
            DiagonalLinear_wide<<<grid, 1024, 0, stream>>>(
                (const f32x4*)x, (const f32x4*)diag, (f32x4*)out, chunk);
            return;
        }
    }
    // Chunked path: 2048 blocks x 256 threads.
    {
        const int grid = 2048;
        const unsigned int chunk = n4 / grid;
        if ((long long)grid * chunk == (long long)n4 &&
            (chunk & (CH4 - 1)) == 0 && ((chunk >> 8) & 3) == 0) {
            DiagonalLinear_chunked<<<grid, 256, 0, stream>>>(
                (const f32x4*)x, (const f32x4*)diag, (f32x4*)out, chunk);
            return;
        }
    }
    // General path.
    const int block = 256;
    long long want = ((long long)n4 + block - 1) / block;
    int g = (int)(want < 2048 ? want : 2048);
    const unsigned int stride = (unsigned int)g * block;
    if ((stride & (CH4 - 1)) == 0) {
        DiagonalLinear_gs<true><<<g, block, 0, stream>>>(
            (const f32x4*)x, (const f32x4*)diag, (f32x4*)out, n4);
    } else {
        DiagonalLinear_gs<false><<<g, block, 0, stream>>>(
            (const f32x4*)x, (const f32x4*)diag, (f32x4*)out, n4);
    }
}